// Round 5
// baseline (242.184 us; speedup 1.0000x reference)
//
#include <hip/hip_runtime.h>
#include <hip/hip_bf16.h>

typedef __attribute__((ext_vector_type(8))) __bf16 bf16x8;
typedef __attribute__((ext_vector_type(4))) float f32x4;

#define MFMA16(a, b, c) __builtin_amdgcn_mfma_f32_16x16x32_bf16((a), (b), (c), 0, 0, 0)

__device__ __forceinline__ unsigned short f2bf(float f) {
    unsigned u = __builtin_bit_cast(unsigned, f);
    u = (u + 0x7fffu + ((u >> 16) & 1u)) >> 16;
    return (unsigned short)u;
}

__device__ __forceinline__ unsigned cvt_pk_bf16(float lo, float hi) {
    unsigned r;
    asm("v_cvt_pk_bf16_f32 %0, %1, %2" : "=v"(r) : "v"(lo), "v"(hi));
    return r;
}

__device__ __forceinline__ void gll16(const void* g, void* l) {
    __builtin_amdgcn_global_load_lds((const __attribute__((address_space(1))) void*)g,
                                     (__attribute__((address_space(3))) void*)l, 16, 0, 0);
}

// ---------------- fp32 -> bf16 convert (vectorized, G13) ----------------
__global__ __launch_bounds__(256) void cvt_f32_bf16(const float4* __restrict__ in,
                                                    ushort4* __restrict__ out, int n4) {
    int i = blockIdx.x * 256 + threadIdx.x;
    if (i >= n4) return;
    float4 v = in[i];
    ushort4 o;
    o.x = f2bf(v.x); o.y = f2bf(v.y); o.z = f2bf(v.z); o.w = f2bf(v.w);
    out[i] = o;
}

// ---------------- RoPE cos/sin table ----------------
__global__ __launch_bounds__(256) void trig_table(float2* __restrict__ tbl) {
    int i = blockIdx.x * 256 + threadIdx.x;   // 65536 = 2048*32
    int t = i >> 5, j = i & 31;
    float inv = powf(10000.0f, -(float)(2 * j) * (1.0f / 64.0f));
    float a = (float)t * inv;
    tbl[i] = make_float2(cosf(a), sinf(a));
}

// ---------------- GEMM: C(MxN) = A(MxK) @ Bt(NxK)^T, bf16 in, fp32 out ----------------
__global__ __launch_bounds__(256) void gemm_bt(const unsigned short* __restrict__ A,
                                               const unsigned short* __restrict__ Bt,
                                               float* __restrict__ C, int M, int N, int K) {
    __shared__ unsigned short As[2][128 * 32];
    __shared__ unsigned short Bs[2][128 * 32];
    const int tid = threadIdx.x;
    const int wid = tid >> 6, lane = tid & 63;
    const size_t brow = (size_t)blockIdx.x * 128, bcol = (size_t)blockIdx.y * 128;
    const int nkt = K >> 5;

    auto stage = [&](int buf, int kt) {
#pragma unroll
        for (int j = 0; j < 2; ++j) {
            int e = (j * 256 + tid) * 8;
            int r = e >> 5, c = e & 31;
            gll16(A + (brow + r) * K + kt * 32 + c, &As[buf][e]);
        }
#pragma unroll
        for (int j = 0; j < 2; ++j) {
            int e = (j * 256 + tid) * 8;
            int r = e >> 5, c = e & 31;
            gll16(Bt + (bcol + r) * K + kt * 32 + c, &Bs[buf][e]);
        }
    };

    f32x4 acc[4][4] = {};
    const int wm = (wid >> 1) * 64, wn = (wid & 1) * 64;
    const int fr = lane & 15, fk = (lane >> 4) * 8;

    stage(0, 0);
    for (int kt = 0; kt < nkt; ++kt) {
        __syncthreads();
        if (kt + 1 < nkt) stage((kt + 1) & 1, kt + 1);
        const int buf = kt & 1;
        bf16x8 af[4], bfr[4];
#pragma unroll
        for (int i = 0; i < 4; ++i)
            af[i] = *(const bf16x8*)&As[buf][(wm + i * 16 + fr) * 32 + fk];
#pragma unroll
        for (int i = 0; i < 4; ++i)
            bfr[i] = *(const bf16x8*)&Bs[buf][(wn + i * 16 + fr) * 32 + fk];
#pragma unroll
        for (int i = 0; i < 4; ++i)
#pragma unroll
            for (int j = 0; j < 4; ++j)
                acc[i][j] = MFMA16(af[i], bfr[j], acc[i][j]);
    }

    const int orow = (lane >> 4) * 4, ocol = lane & 15;
#pragma unroll
    for (int i = 0; i < 4; ++i)
#pragma unroll
        for (int j = 0; j < 4; ++j)
#pragma unroll
            for (int r = 0; r < 4; ++r)
                C[(brow + wm + i * 16 + orow + r) * N + (bcol + wn + j * 16 + ocol)] =
                    acc[i][j][r];
}

// ---------------- RoPE + QK-RMSNorm + layout split (q pre-scaled by 1/sqrt(D)) ----------------
__global__ __launch_bounds__(256) void rope_norm(const float* __restrict__ qkv,
                                                 const float2* __restrict__ tbl,
                                                 unsigned short* __restrict__ qb,
                                                 unsigned short* __restrict__ kb,
                                                 unsigned short* __restrict__ vb) {
    int unit = blockIdx.x * 4 + (threadIdx.x >> 6);
    int lane = threadIdx.x & 63;
    int row = unit / 24;
    int hh = unit - row * 24;
    int b = row >> 11, t = row & 2047;
    int col = (hh < 16) ? hh * 64 : (hh < 20 ? 1024 + (hh - 16) * 64 : 1280 + (hh - 20) * 64);
    float x = qkv[(size_t)row * 1536 + col + lane];
    float o = x;
    if (hh < 20) {
        float partner = __shfl_xor(x, 1);
        float2 cs = tbl[t * 32 + (lane >> 1)];
        float sgn = (lane & 1) ? cs.y : -cs.y;
        o = x * cs.x + partner * sgn;
        float ss = o * o;
#pragma unroll
        for (int off = 1; off < 64; off <<= 1) ss += __shfl_xor(ss, off);
        o = o * rsqrtf(ss * (1.0f / 64.0f) + 1e-6f);
        if (hh < 16) o *= 0.125f;
    }
    unsigned short ob = f2bf(o);
    if (hh < 16)
        qb[(((size_t)(b * 16 + hh)) * 2048 + t) * 64 + lane] = ob;
    else if (hh < 20)
        kb[(((size_t)(b * 4 + (hh - 16))) * 2048 + t) * 64 + lane] = ob;
    else
        vb[(((size_t)(b * 4 + (hh - 20))) * 2048 + t) * 64 + lane] = ob;
}

// ---------------- V transpose: [B*KVH][T][D] -> [B*KVH][D][T] ----------------
__global__ __launch_bounds__(256) void vtrans(const unsigned short* __restrict__ vb,
                                              unsigned short* __restrict__ vt) {
    __shared__ unsigned short tile[64][72];
    int bk = blockIdx.y, t0 = blockIdx.x * 64;
    int i = threadIdx.x >> 2, c0 = (threadIdx.x & 3) * 16;
    const unsigned short* src = vb + ((size_t)bk * 2048 + t0) * 64;
#pragma unroll
    for (int j = 0; j < 16; ++j) tile[i][c0 + j] = src[i * 64 + c0 + j];
    __syncthreads();
    unsigned short* dst = vt + (size_t)bk * 64 * 2048 + (size_t)i * 2048 + t0 + c0;
#pragma unroll
    for (int j = 0; j < 16; ++j) dst[j] = tile[c0 + j][i];
}

// ---------------- causal flash attention: kv-split partials, static-max softmax ----------------
// Fixed softmax shift (p = exp(s-8)) => partial (accO, accL) over any kv-chunk combine by
// pure addition. Each q-tile's kv-range splits into <=4 near-equal chunks -> 2560 uniform
// blocks; partials atomicAdd'd (fp32) into zeroed global buffers; finalize divides.
// K/V staged in LDS (dbuf, global_load_lds, XOR-chunk swizzle both sides); XCD-chunked grid.
#define PSTRIDE 76
__global__ __launch_bounds__(256) void attn_fwd(const unsigned short* __restrict__ qb,
                                                const unsigned short* __restrict__ kbuf,
                                                const unsigned short* __restrict__ vt,
                                                float* __restrict__ accOg,
                                                float* __restrict__ accLg) {
    // XCD-chunked bijective swizzle (nwg=2560 = 8*320; 320 = 8 bh per XCD chunk)
    int orig = blockIdx.x;
    int wg = (orig & 7) * 320 + (orig >> 3);
    int bh = wg / 40;
    int u = 39 - (wg - bh * 40);          // heavy-first (large qt first)
    int qt, ci, nc;
    if (u < 4)       { qt = u;               ci = 0;            nc = 1; }
    else if (u < 12) { qt = 4 + ((u - 4) >> 1);  ci = (u - 4) & 1;  nc = 2; }
    else if (u < 24) { qt = 8 + (u - 12) / 3;    ci = (u - 12) % 3; nc = 3; }
    else             { qt = 12 + ((u - 24) >> 2); ci = (u - 24) & 3; nc = 4; }
    const int nkt = 2 * qt + 2;           // 64-key tiles covering keys 0..qbase+127
    const int t0 = ci * nkt / nc, t1 = (ci + 1) * nkt / nc;
    const int qbase = qt * 128;

    int b = bh >> 4, h = bh & 15, kvh = h >> 2;
    int tid = threadIdx.x, wid = tid >> 6, lane = tid & 63;
    int qrow0 = qbase + wid * 32;
    const unsigned short* Q = qb + ((size_t)(b * 16 + h)) * 2048 * 64;
    const unsigned short* Kp = kbuf + ((size_t)(b * 4 + kvh)) * 2048 * 64;
    const unsigned short* Vp = vt + ((size_t)(b * 4 + kvh)) * 64 * 2048;
    const int fr = lane & 15, fk8 = (lane >> 4) * 8, rbase = (lane >> 4) * 4;

    __shared__ unsigned short Klds[2][4096];
    __shared__ unsigned short Vlds[2][4096];
    __shared__ unsigned short sP[4][32 * PSTRIDE];
    unsigned short* myP = sP[wid];

    auto stage = [&](int buf, int kt) {
#pragma unroll
        for (int j = 0; j < 2; ++j) {
            int t = j * 256 + tid;
            int k = t >> 3, c = (t & 7) ^ (k & 7);
            gll16(Kp + ((size_t)(kt * 64 + k)) * 64 + c * 8, &Klds[buf][t * 8]);
        }
#pragma unroll
        for (int j = 0; j < 2; ++j) {
            int t = j * 256 + tid;
            int d = t >> 3, c = (t & 7) ^ (d & 7);
            gll16(Vp + (size_t)d * 2048 + kt * 64 + c * 8, &Vlds[buf][t * 8]);
        }
    };

    bf16x8 qf[2][2];
#pragma unroll
    for (int m = 0; m < 2; ++m) {
        qf[m][0] = *(const bf16x8*)&Q[(qrow0 + m * 16 + fr) * 64 + fk8];
        qf[m][1] = *(const bf16x8*)&Q[(qrow0 + m * 16 + fr) * 64 + 32 + fk8];
    }

    bf16x8 onesf;
#pragma unroll
    for (int i = 0; i < 8; ++i) onesf[i] = (__bf16)1.0f;

    f32x4 accO[2][4] = {};
    f32x4 accL[2] = {};

    stage(0, t0);
    for (int kt = t0; kt < t1; ++kt) {
        __syncthreads();                   // drains stage(kt) vmcnt; guards buf reuse
        if (kt + 1 < t1) stage((kt + 1 - t0) & 1, kt + 1);
        const int cur = (kt - t0) & 1;
        const int kb0 = kt * 64;
        if (kb0 <= qrow0 + 31) {           // wave-uniform causal skip
            f32x4 s[2][4] = {};
#pragma unroll
            for (int j = 0; j < 4; ++j) {
                int row = j * 16 + fr, sw = (row & 7) << 3;
                bf16x8 kf0 = *(const bf16x8*)&Klds[cur][row * 64 + (fk8 ^ sw)];
                bf16x8 kf1 = *(const bf16x8*)&Klds[cur][row * 64 + ((32 + fk8) ^ sw)];
#pragma unroll
                for (int m = 0; m < 2; ++m) {
                    s[m][j] = MFMA16(kf0, qf[m][0], s[m][j]);
                    s[m][j] = MFMA16(kf1, qf[m][1], s[m][j]);
                }
            }
            // p = exp(s-8): static max (|q_hat . k| <= 8 after rms-norm + 1/sqrt(D))
            const bool diag = (kb0 + 63 > qrow0);
#pragma unroll
            for (int m = 0; m < 2; ++m) {
                int q = qrow0 + m * 16 + fr;
#pragma unroll
                for (int j = 0; j < 4; ++j) {
                    float p[4];
#pragma unroll
                    for (int r = 0; r < 4; ++r) {
                        p[r] = __builtin_exp2f(fmaf(s[m][j][r], 1.44269504f, -11.54156036f));
                        if (diag && (kb0 + j * 16 + rbase + r > q)) p[r] = 0.0f;
                    }
                    uint2 w;
                    w.x = cvt_pk_bf16(p[0], p[1]);
                    w.y = cvt_pk_bf16(p[2], p[3]);
                    *(uint2*)&myP[(m * 16 + fr) * PSTRIDE + j * 16 + rbase] = w;
                }
            }
            bf16x8 vf[4][2];
#pragma unroll
            for (int nd = 0; nd < 4; ++nd) {
                int row = nd * 16 + fr, sw = (row & 7) << 3;
                vf[nd][0] = *(const bf16x8*)&Vlds[cur][row * 64 + (fk8 ^ sw)];
                vf[nd][1] = *(const bf16x8*)&Vlds[cur][row * 64 + ((32 + fk8) ^ sw)];
            }
            asm volatile("s_waitcnt lgkmcnt(0)" ::: "memory");
            __builtin_amdgcn_sched_barrier(0);
#pragma unroll
            for (int m = 0; m < 2; ++m) {
                bf16x8 pf0 = *(const bf16x8*)&myP[(m * 16 + fr) * PSTRIDE + fk8];
                bf16x8 pf1 = *(const bf16x8*)&myP[(m * 16 + fr) * PSTRIDE + 32 + fk8];
#pragma unroll
                for (int nd = 0; nd < 4; ++nd) {
                    accO[m][nd] = MFMA16(pf0, vf[nd][0], accO[m][nd]);
                    accO[m][nd] = MFMA16(pf1, vf[nd][1], accO[m][nd]);
                }
                accL[m] = MFMA16(pf0, onesf, accL[m]);
                accL[m] = MFMA16(pf1, onesf, accL[m]);
            }
            asm volatile("" ::: "memory");
        }
    }

    // additive combine: fp32 atomics into zeroed partial buffers
    if (t0 * 64 <= qrow0 + 31) {          // this wave contributed
#pragma unroll
        for (int m = 0; m < 2; ++m)
#pragma unroll
            for (int r = 0; r < 4; ++r) {
                int row = qrow0 + m * 16 + rbase + r;
                float* dst = accOg + ((size_t)bh * 2048 + row) * 64;
#pragma unroll
                for (int nd = 0; nd < 4; ++nd)
                    atomicAdd(&dst[nd * 16 + fr], accO[m][nd][r]);
                if (fr == 0) atomicAdd(&accLg[(size_t)bh * 2048 + row], accL[m][r]);
            }
    }
}

// ---------------- finalize: y = accO / accL -> bf16 [b][t][h*64+d] ----------------
__global__ __launch_bounds__(256) void attn_fin(const float* __restrict__ accOg,
                                                const float* __restrict__ accLg,
                                                unsigned short* __restrict__ y) {
    int idx = blockIdx.x * 256 + threadIdx.x;   // 2,097,152 = 64*2048*16
    int dg = idx & 15;
    int row = idx >> 4;
    int bh = row >> 11, t = row & 2047;
    int b = bh >> 4, h = bh & 15;
    f32x4 o = *(const f32x4*)&accOg[(size_t)row * 64 + dg * 4];
    float inv = 1.0f / accLg[row];
    ushort4 w;
    w.x = f2bf(o[0] * inv); w.y = f2bf(o[1] * inv);
    w.z = f2bf(o[2] * inv); w.w = f2bf(o[3] * inv);
    *(ushort4*)&y[((size_t)(b * 2048 + t)) * 1024 + h * 64 + dg * 4] = w;
}

extern "C" void kernel_launch(void* const* d_in, const int* in_sizes, int n_in,
                              void* d_out, int out_size, void* d_ws, size_t ws_size,
                              hipStream_t stream) {
    const float* x = (const float*)d_in[0];
    const float* wq = (const float*)d_in[1];
    const float* wk = (const float*)d_in[2];
    const float* wv = (const float*)d_in[3];
    const float* wo = (const float*)d_in[4];
    float* out = (float*)d_out;

    char* ws = (char*)d_ws;
    size_t off = 0;
    auto alloc = [&](size_t bytes) {
        void* p = ws + off;
        off += (bytes + 255) & ~(size_t)255;
        return p;
    };
    unsigned short* xb    = (unsigned short*)alloc(8192ull * 1024 * 2);   // dead after gemm1; reused as ybf
    unsigned short* wqkvb = (unsigned short*)alloc(1536ull * 1024 * 2);
    unsigned short* wob   = (unsigned short*)alloc(1024ull * 1024 * 2);
    float*          qkv   = (float*)alloc(8192ull * 1536 * 4);            // dead after rope_norm; reused as accO/accL
    float2*         tbl   = (float2*)alloc(2048ull * 32 * 8);
    unsigned short* qb    = (unsigned short*)alloc(8192ull * 1024 * 2);
    unsigned short* kb    = (unsigned short*)alloc(4ull * 4 * 2048 * 64 * 2);
    unsigned short* vb    = (unsigned short*)alloc(4ull * 4 * 2048 * 64 * 2);
    unsigned short* vt    = (unsigned short*)alloc(4ull * 4 * 64 * 2048 * 2);

    float*          accO  = qkv;                                 // 64*2048*64 f32 = 32MB
    float*          accL  = qkv + 64ull * 2048 * 64;             // 64*2048 f32 = 512KB
    unsigned short* ybf   = xb;                                  // 16MB

    cvt_f32_bf16<<<(2097152 + 255) / 256, 256, 0, stream>>>((const float4*)x, (ushort4*)xb, 2097152);
    cvt_f32_bf16<<<(262144 + 255) / 256, 256, 0, stream>>>((const float4*)wq, (ushort4*)wqkvb, 262144);
    cvt_f32_bf16<<<(65536 + 255) / 256, 256, 0, stream>>>((const float4*)wk, (ushort4*)(wqkvb + 1048576), 65536);
    cvt_f32_bf16<<<(65536 + 255) / 256, 256, 0, stream>>>((const float4*)wv, (ushort4*)(wqkvb + 1310720), 65536);
    cvt_f32_bf16<<<(262144 + 255) / 256, 256, 0, stream>>>((const float4*)wo, (ushort4*)wob, 262144);

    trig_table<<<256, 256, 0, stream>>>(tbl);

    gemm_bt<<<dim3(64, 12), 256, 0, stream>>>(xb, wqkvb, qkv, 8192, 1536, 1024);

    rope_norm<<<(8192 * 24) / 4, 256, 0, stream>>>(qkv, tbl, qb, kb, vb);

    vtrans<<<dim3(32, 16), 256, 0, stream>>>(vb, vt);

    // zero partial buffers (qkv is dead now); stream-ordered after rope_norm
    hipMemsetAsync(accO, 0, (64ull * 2048 * 64 + 64ull * 2048) * 4, stream);

    attn_fwd<<<2560, 256, 0, stream>>>(qb, kb, vt, accO, accL);

    attn_fin<<<8192, 256, 0, stream>>>(accO, accL, ybf);

    gemm_bt<<<dim3(64, 8), 256, 0, stream>>>(ybf, wob, out, 8192, 1024, 1024);
}

// Round 6
// 218.963 us; speedup vs baseline: 1.1061x; 1.1061x over previous
//
#include <hip/hip_runtime.h>
#include <hip/hip_bf16.h>

typedef __attribute__((ext_vector_type(8))) __bf16 bf16x8;
typedef __attribute__((ext_vector_type(4))) float f32x4;
typedef __attribute__((ext_vector_type(16))) float f32x16;

#define MFMA16(a, b, c) __builtin_amdgcn_mfma_f32_16x16x32_bf16((a), (b), (c), 0, 0, 0)
#define MFMA32(a, b, c) __builtin_amdgcn_mfma_f32_32x32x16_bf16((a), (b), (c), 0, 0, 0)

__device__ __forceinline__ unsigned short f2bf(float f) {
    unsigned u = __builtin_bit_cast(unsigned, f);
    u = (u + 0x7fffu + ((u >> 16) & 1u)) >> 16;
    return (unsigned short)u;
}

__device__ __forceinline__ unsigned cvt_pk_bf16(float lo, float hi) {
    unsigned r;
    asm("v_cvt_pk_bf16_f32 %0, %1, %2" : "=v"(r) : "v"(lo), "v"(hi));
    return r;
}

// swaps a.hi32lanes <-> b.lo32lanes; after: a = {a.lo, b.lo}, b = {a.hi, b.hi}
__device__ __forceinline__ void permswap(unsigned& a, unsigned& b) {
    asm("v_permlane32_swap_b32 %0, %1" : "+v"(a), "+v"(b));
}

__device__ __forceinline__ void gll16(const void* g, void* l) {
    __builtin_amdgcn_global_load_lds((const __attribute__((address_space(1))) void*)g,
                                     (__attribute__((address_space(3))) void*)l, 16, 0, 0);
}

// ---------------- fp32 -> bf16 convert (vectorized, G13) ----------------
__global__ __launch_bounds__(256) void cvt_f32_bf16(const float4* __restrict__ in,
                                                    ushort4* __restrict__ out, int n4) {
    int i = blockIdx.x * 256 + threadIdx.x;
    if (i >= n4) return;
    float4 v = in[i];
    ushort4 o;
    o.x = f2bf(v.x); o.y = f2bf(v.y); o.z = f2bf(v.z); o.w = f2bf(v.w);
    out[i] = o;
}

// ---------------- RoPE cos/sin table ----------------
__global__ __launch_bounds__(256) void trig_table(float2* __restrict__ tbl) {
    int i = blockIdx.x * 256 + threadIdx.x;   // 65536 = 2048*32
    int t = i >> 5, j = i & 31;
    float inv = powf(10000.0f, -(float)(2 * j) * (1.0f / 64.0f));
    float a = (float)t * inv;
    tbl[i] = make_float2(cosf(a), sinf(a));
}

// ---------------- GEMM: C(MxN) = A(MxK) @ Bt(NxK)^T, bf16 in, fp32 out ----------------
__global__ __launch_bounds__(256) void gemm_bt(const unsigned short* __restrict__ A,
                                               const unsigned short* __restrict__ Bt,
                                               float* __restrict__ C, int M, int N, int K) {
    __shared__ unsigned short As[2][128 * 32];
    __shared__ unsigned short Bs[2][128 * 32];
    const int tid = threadIdx.x;
    const int wid = tid >> 6, lane = tid & 63;
    const size_t brow = (size_t)blockIdx.x * 128, bcol = (size_t)blockIdx.y * 128;
    const int nkt = K >> 5;

    auto stage = [&](int buf, int kt) {
#pragma unroll
        for (int j = 0; j < 2; ++j) {
            int e = (j * 256 + tid) * 8;
            int r = e >> 5, c = e & 31;
            gll16(A + (brow + r) * K + kt * 32 + c, &As[buf][e]);
        }
#pragma unroll
        for (int j = 0; j < 2; ++j) {
            int e = (j * 256 + tid) * 8;
            int r = e >> 5, c = e & 31;
            gll16(Bt + (bcol + r) * K + kt * 32 + c, &Bs[buf][e]);
        }
    };

    f32x4 acc[4][4] = {};
    const int wm = (wid >> 1) * 64, wn = (wid & 1) * 64;
    const int fr = lane & 15, fk = (lane >> 4) * 8;

    stage(0, 0);
    for (int kt = 0; kt < nkt; ++kt) {
        __syncthreads();
        if (kt + 1 < nkt) stage((kt + 1) & 1, kt + 1);
        const int buf = kt & 1;
        bf16x8 af[4], bfr[4];
#pragma unroll
        for (int i = 0; i < 4; ++i)
            af[i] = *(const bf16x8*)&As[buf][(wm + i * 16 + fr) * 32 + fk];
#pragma unroll
        for (int i = 0; i < 4; ++i)
            bfr[i] = *(const bf16x8*)&Bs[buf][(wn + i * 16 + fr) * 32 + fk];
#pragma unroll
        for (int i = 0; i < 4; ++i)
#pragma unroll
            for (int j = 0; j < 4; ++j)
                acc[i][j] = MFMA16(af[i], bfr[j], acc[i][j]);
    }

    const int orow = (lane >> 4) * 4, ocol = lane & 15;
#pragma unroll
    for (int i = 0; i < 4; ++i)
#pragma unroll
        for (int j = 0; j < 4; ++j)
#pragma unroll
            for (int r = 0; r < 4; ++r)
                C[(brow + wm + i * 16 + orow + r) * N + (bcol + wn + j * 16 + ocol)] =
                    acc[i][j][r];
}

// ---------------- RoPE + QK-RMSNorm + layout split (q pre-scaled by 1/sqrt(D)) ----------------
__global__ __launch_bounds__(256) void rope_norm(const float* __restrict__ qkv,
                                                 const float2* __restrict__ tbl,
                                                 unsigned short* __restrict__ qb,
                                                 unsigned short* __restrict__ kb,
                                                 unsigned short* __restrict__ vb) {
    int unit = blockIdx.x * 4 + (threadIdx.x >> 6);
    int lane = threadIdx.x & 63;
    int row = unit / 24;
    int hh = unit - row * 24;
    int b = row >> 11, t = row & 2047;
    int col = (hh < 16) ? hh * 64 : (hh < 20 ? 1024 + (hh - 16) * 64 : 1280 + (hh - 20) * 64);
    float x = qkv[(size_t)row * 1536 + col + lane];
    float o = x;
    if (hh < 20) {
        float partner = __shfl_xor(x, 1);
        float2 cs = tbl[t * 32 + (lane >> 1)];
        float sgn = (lane & 1) ? cs.y : -cs.y;
        o = x * cs.x + partner * sgn;
        float ss = o * o;
#pragma unroll
        for (int off = 1; off < 64; off <<= 1) ss += __shfl_xor(ss, off);
        o = o * rsqrtf(ss * (1.0f / 64.0f) + 1e-6f);
        if (hh < 16) o *= 0.125f;
    }
    unsigned short ob = f2bf(o);
    if (hh < 16)
        qb[(((size_t)(b * 16 + hh)) * 2048 + t) * 64 + lane] = ob;
    else if (hh < 20)
        kb[(((size_t)(b * 4 + (hh - 16))) * 2048 + t) * 64 + lane] = ob;
    else
        vb[(((size_t)(b * 4 + (hh - 20))) * 2048 + t) * 64 + lane] = ob;
}

// ---------------- V transpose: [B*KVH][T][D] -> [B*KVH][D][T] ----------------
__global__ __launch_bounds__(256) void vtrans(const unsigned short* __restrict__ vb,
                                              unsigned short* __restrict__ vt) {
    __shared__ unsigned short tile[64][72];
    int bk = blockIdx.y, t0 = blockIdx.x * 64;
    int i = threadIdx.x >> 2, c0 = (threadIdx.x & 3) * 16;
    const unsigned short* src = vb + ((size_t)bk * 2048 + t0) * 64;
#pragma unroll
    for (int j = 0; j < 16; ++j) tile[i][c0 + j] = src[i * 64 + c0 + j];
    __syncthreads();
    unsigned short* dst = vt + (size_t)bk * 64 * 2048 + (size_t)i * 2048 + t0 + c0;
#pragma unroll
    for (int j = 0; j < 16; ++j) dst[j] = tile[c0 + j][i];
}

// ---------------- causal flash attention: 32x32 MFMA, in-register softmax (T12) ----------------
// Swapped QK^T (S^T = K@Q^T): each lane owns one q-column (q = lane&31); P->A-fragment built
// in registers via cvt_pk + permlane32_swap (no LDS round trip, no lgkm pins). Static-max
// softmax (p=exp(s-8)), denominator = lane-local f32 sum + one end-of-loop permlane merge.
// K/V staged in LDS (dbuf, global_load_lds, XOR chunk swizzle); kv-split chunks + atomics.
__global__ __launch_bounds__(256) void attn_fwd(const unsigned short* __restrict__ qb,
                                                const unsigned short* __restrict__ kbuf,
                                                const unsigned short* __restrict__ vt,
                                                float* __restrict__ accOg,
                                                float* __restrict__ accLg) {
    // XCD-chunked bijective swizzle (nwg=2560 = 8*320; 320 = 8 bh per XCD chunk)
    int orig = blockIdx.x;
    int wg = (orig & 7) * 320 + (orig >> 3);
    int bh = wg / 40;
    int u = 39 - (wg - bh * 40);          // heavy-first (large qt first)
    int qt, ci, nc;
    if (u < 4)       { qt = u;               ci = 0;            nc = 1; }
    else if (u < 12) { qt = 4 + ((u - 4) >> 1);  ci = (u - 4) & 1;  nc = 2; }
    else if (u < 24) { qt = 8 + (u - 12) / 3;    ci = (u - 12) % 3; nc = 3; }
    else             { qt = 12 + ((u - 24) >> 2); ci = (u - 24) & 3; nc = 4; }
    const int nkt = 2 * qt + 2;
    const int t0 = ci * nkt / nc, t1 = (ci + 1) * nkt / nc;
    const int qbase = qt * 128;

    int b = bh >> 4, h = bh & 15, kvh = h >> 2;
    int tid = threadIdx.x, wid = tid >> 6, lane = tid & 63;
    int qrow0 = qbase + wid * 32;
    const unsigned short* Q = qb + ((size_t)(b * 16 + h)) * 2048 * 64;
    const unsigned short* Kp = kbuf + ((size_t)(b * 4 + kvh)) * 2048 * 64;
    const unsigned short* Vp = vt + ((size_t)(b * 4 + kvh)) * 64 * 2048;
    const int q32 = lane & 31, hi = lane >> 5, swz = q32 & 7;

    __shared__ unsigned short Klds[2][4096];   // [64 keys][64 d], chunk-swizzled
    __shared__ unsigned short Vlds[2][4096];   // [64 d][64 keys], chunk-swizzled

    auto stage = [&](int buf, int kt) {
#pragma unroll
        for (int j = 0; j < 2; ++j) {
            int t = j * 256 + tid;
            int k = t >> 3, c = (t & 7) ^ (k & 7);
            gll16(Kp + ((size_t)(kt * 64 + k)) * 64 + c * 8, &Klds[buf][t * 8]);
        }
#pragma unroll
        for (int j = 0; j < 2; ++j) {
            int t = j * 256 + tid;
            int d = t >> 3, c = (t & 7) ^ (d & 7);
            gll16(Vp + (size_t)d * 2048 + kt * 64 + c * 8, &Vlds[buf][t * 8]);
        }
    };

    // Q fragments (B-operand): lane holds Q[qrow0+q32][kd*16 + hi*8 .. +7]
    bf16x8 qf[4];
#pragma unroll
    for (int kd = 0; kd < 4; ++kd)
        qf[kd] = *(const bf16x8*)&Q[(qrow0 + q32) * 64 + kd * 16 + hi * 8];

    f32x16 accO[2] = {};
    float lrun = 0.0f;

    stage(0, t0);
    for (int kt = t0; kt < t1; ++kt) {
        __syncthreads();                   // drains stage(kt) vmcnt; guards buf reuse
        if (kt + 1 < t1) stage((kt + 1 - t0) & 1, kt + 1);
        const int cur = (kt - t0) & 1;
        const int kb0 = kt * 64;
        if (kb0 <= qrow0 + 31) {           // wave-uniform causal skip
            // S^T = K @ Q^T: two 32-key tiles, 4 d-slices each
            f32x16 s[2] = {};
#pragma unroll
            for (int j = 0; j < 2; ++j) {
                int row = j * 32 + q32;
#pragma unroll
                for (int kd = 0; kd < 4; ++kd) {
                    bf16x8 kf = *(const bf16x8*)&Klds[cur][row * 64 + ((2 * kd + hi) ^ swz) * 8];
                    s[j] = MFMA32(kf, qf[kd], s[j]);
                }
            }
            const bool diag = (kb0 + 63 > qrow0);
            const int qg = qrow0 + q32;
            bf16x8 pf[4];                  // P A/B-fragment, key-slices of 16
#pragma unroll
            for (int j = 0; j < 2; ++j) {
                float p[16];
#pragma unroll
                for (int r = 0; r < 16; ++r) {
                    float v = __builtin_exp2f(fmaf(s[j][r], 1.44269504f, -11.54156036f));
                    if (diag) {
                        int key = kb0 + j * 32 + (r & 3) + 8 * (r >> 2) + 4 * hi;
                        if (key > qg) v = 0.0f;
                    }
                    lrun += v;
                    p[r] = v;
                }
#pragma unroll
                for (int kl = 0; kl < 2; ++kl) {
                    unsigned c0 = cvt_pk_bf16(p[8 * kl + 0], p[8 * kl + 1]);
                    unsigned c1 = cvt_pk_bf16(p[8 * kl + 4], p[8 * kl + 5]);
                    unsigned c2 = cvt_pk_bf16(p[8 * kl + 2], p[8 * kl + 3]);
                    unsigned c3 = cvt_pk_bf16(p[8 * kl + 6], p[8 * kl + 7]);
                    permswap(c0, c1);      // c0 = word0, c1 = word2
                    permswap(c2, c3);      // c2 = word1, c3 = word3
                    union { bf16x8 v; unsigned u[4]; } pk;
                    pk.u[0] = c0; pk.u[1] = c2; pk.u[2] = c1; pk.u[3] = c3;
                    pf[j * 2 + kl] = pk.v;
                }
            }
            // O += P @ V : V^T rows (d) contiguous over keys in Vlds
#pragma unroll
            for (int nd = 0; nd < 2; ++nd) {
                int row = nd * 32 + q32;
#pragma unroll
                for (int ks = 0; ks < 4; ++ks) {
                    bf16x8 vf = *(const bf16x8*)&Vlds[cur][row * 64 + ((2 * ks + hi) ^ swz) * 8];
                    accO[nd] = MFMA32(pf[ks], vf, accO[nd]);
                }
            }
        }
    }

    // cross-half denominator merge: lane halves hold disjoint key subsets for same q
    unsigned lu = __builtin_bit_cast(unsigned, lrun);
    unsigned la = lu, lb = lu;
    permswap(la, lb);                      // la = lo-half's sums (both halves), lb = hi-half's
    float L = __builtin_bit_cast(float, la) + __builtin_bit_cast(float, lb);

    // additive combine: fp32 atomics into zeroed partial buffers
    if (t0 * 64 <= qrow0 + 31) {
#pragma unroll
        for (int nd = 0; nd < 2; ++nd)
#pragma unroll
            for (int r = 0; r < 16; ++r) {
                int rowq = qrow0 + (r & 3) + 8 * (r >> 2) + 4 * hi;
                atomicAdd(accOg + ((size_t)bh * 2048 + rowq) * 64 + nd * 32 + q32, accO[nd][r]);
            }
        if (lane < 32) atomicAdd(accLg + (size_t)bh * 2048 + qrow0 + q32, L);
    }
}

// ---------------- finalize: y = accO / accL -> bf16 [b][t][h*64+d] ----------------
__global__ __launch_bounds__(256) void attn_fin(const float* __restrict__ accOg,
                                                const float* __restrict__ accLg,
                                                unsigned short* __restrict__ y) {
    int idx = blockIdx.x * 256 + threadIdx.x;   // 2,097,152 = 64*2048*16
    int dg = idx & 15;
    int row = idx >> 4;
    int bh = row >> 11, t = row & 2047;
    int b = bh >> 4, h = bh & 15;
    f32x4 o = *(const f32x4*)&accOg[(size_t)row * 64 + dg * 4];
    float inv = 1.0f / accLg[row];
    ushort4 w;
    w.x = f2bf(o[0] * inv); w.y = f2bf(o[1] * inv);
    w.z = f2bf(o[2] * inv); w.w = f2bf(o[3] * inv);
    *(ushort4*)&y[((size_t)(b * 2048 + t)) * 1024 + h * 64 + dg * 4] = w;
}

extern "C" void kernel_launch(void* const* d_in, const int* in_sizes, int n_in,
                              void* d_out, int out_size, void* d_ws, size_t ws_size,
                              hipStream_t stream) {
    const float* x = (const float*)d_in[0];
    const float* wq = (const float*)d_in[1];
    const float* wk = (const float*)d_in[2];
    const float* wv = (const float*)d_in[3];
    const float* wo = (const float*)d_in[4];
    float* out = (float*)d_out;

    char* ws = (char*)d_ws;
    size_t off = 0;
    auto alloc = [&](size_t bytes) {
        void* p = ws + off;
        off += (bytes + 255) & ~(size_t)255;
        return p;
    };
    unsigned short* xb    = (unsigned short*)alloc(8192ull * 1024 * 2);   // dead after gemm1; reused as ybf
    unsigned short* wqkvb = (unsigned short*)alloc(1536ull * 1024 * 2);
    unsigned short* wob   = (unsigned short*)alloc(1024ull * 1024 * 2);
    float*          qkv   = (float*)alloc(8192ull * 1536 * 4);            // dead after rope_norm; reused as accO/accL
    float2*         tbl   = (float2*)alloc(2048ull * 32 * 8);
    unsigned short* qb    = (unsigned short*)alloc(8192ull * 1024 * 2);
    unsigned short* kb    = (unsigned short*)alloc(4ull * 4 * 2048 * 64 * 2);
    unsigned short* vb    = (unsigned short*)alloc(4ull * 4 * 2048 * 64 * 2);
    unsigned short* vt    = (unsigned short*)alloc(4ull * 4 * 64 * 2048 * 2);

    float*          accO  = qkv;                                 // 64*2048*64 f32 = 32MB
    float*          accL  = qkv + 64ull * 2048 * 64;             // 64*2048 f32 = 512KB
    unsigned short* ybf   = xb;                                  // 16MB

    cvt_f32_bf16<<<(2097152 + 255) / 256, 256, 0, stream>>>((const float4*)x, (ushort4*)xb, 2097152);
    cvt_f32_bf16<<<(262144 + 255) / 256, 256, 0, stream>>>((const float4*)wq, (ushort4*)wqkvb, 262144);
    cvt_f32_bf16<<<(65536 + 255) / 256, 256, 0, stream>>>((const float4*)wk, (ushort4*)(wqkvb + 1048576), 65536);
    cvt_f32_bf16<<<(65536 + 255) / 256, 256, 0, stream>>>((const float4*)wv, (ushort4*)(wqkvb + 1310720), 65536);
    cvt_f32_bf16<<<(262144 + 255) / 256, 256, 0, stream>>>((const float4*)wo, (ushort4*)wob, 262144);

    trig_table<<<256, 256, 0, stream>>>(tbl);

    gemm_bt<<<dim3(64, 12), 256, 0, stream>>>(xb, wqkvb, qkv, 8192, 1536, 1024);

    rope_norm<<<(8192 * 24) / 4, 256, 0, stream>>>(qkv, tbl, qb, kb, vb);

    vtrans<<<dim3(32, 16), 256, 0, stream>>>(vb, vt);

    // zero partial buffers (qkv is dead now); stream-ordered after rope_norm
    hipMemsetAsync(accO, 0, (64ull * 2048 * 64 + 64ull * 2048) * 4, stream);

    attn_fwd<<<2560, 256, 0, stream>>>(qb, kb, vt, accO, accL);

    attn_fin<<<8192, 256, 0, stream>>>(accO, accL, ybf);

    gemm_bt<<<dim3(64, 8), 256, 0, stream>>>(ybf, wob, out, 8192, 1024, 1024);
}

// Round 7
// 214.573 us; speedup vs baseline: 1.1287x; 1.0205x over previous
//
#include <hip/hip_runtime.h>
#include <hip/hip_bf16.h>

typedef __attribute__((ext_vector_type(8))) __bf16 bf16x8;
typedef __attribute__((ext_vector_type(2))) float f32x2;
typedef __attribute__((ext_vector_type(4))) float f32x4;
typedef __attribute__((ext_vector_type(16))) float f32x16;

#define MFMA16(a, b, c) __builtin_amdgcn_mfma_f32_16x16x32_bf16((a), (b), (c), 0, 0, 0)
#define MFMA32(a, b, c) __builtin_amdgcn_mfma_f32_32x32x16_bf16((a), (b), (c), 0, 0, 0)

template <bool B> struct BoolC { static constexpr bool value = B; };

__device__ __forceinline__ unsigned short f2bf(float f) {
    unsigned u = __builtin_bit_cast(unsigned, f);
    u = (u + 0x7fffu + ((u >> 16) & 1u)) >> 16;
    return (unsigned short)u;
}

__device__ __forceinline__ unsigned cvt_pk_bf16(float lo, float hi) {
    unsigned r;
    asm("v_cvt_pk_bf16_f32 %0, %1, %2" : "=v"(r) : "v"(lo), "v"(hi));
    return r;
}

// swaps a.hi32lanes <-> b.lo32lanes
__device__ __forceinline__ void permswap(unsigned& a, unsigned& b) {
    asm("v_permlane32_swap_b32 %0, %1" : "+v"(a), "+v"(b));
}

__device__ __forceinline__ void gll16(const void* g, void* l) {
    __builtin_amdgcn_global_load_lds((const __attribute__((address_space(1))) void*)g,
                                     (__attribute__((address_space(3))) void*)l, 16, 0, 0);
}

// ---------------- fp32 -> bf16 convert (vectorized, G13) ----------------
__global__ __launch_bounds__(256) void cvt_f32_bf16(const float4* __restrict__ in,
                                                    ushort4* __restrict__ out, int n4) {
    int i = blockIdx.x * 256 + threadIdx.x;
    if (i >= n4) return;
    float4 v = in[i];
    ushort4 o;
    o.x = f2bf(v.x); o.y = f2bf(v.y); o.z = f2bf(v.z); o.w = f2bf(v.w);
    out[i] = o;
}

// ---------------- RoPE cos/sin table ----------------
__global__ __launch_bounds__(256) void trig_table(float2* __restrict__ tbl) {
    int i = blockIdx.x * 256 + threadIdx.x;   // 65536 = 2048*32
    int t = i >> 5, j = i & 31;
    float inv = powf(10000.0f, -(float)(2 * j) * (1.0f / 64.0f));
    float a = (float)t * inv;
    tbl[i] = make_float2(cosf(a), sinf(a));
}

// ---------------- GEMM: C(MxN) = A(MxK) @ Bt(NxK)^T, bf16 in, fp32 out ----------------
__global__ __launch_bounds__(256) void gemm_bt(const unsigned short* __restrict__ A,
                                               const unsigned short* __restrict__ Bt,
                                               float* __restrict__ C, int M, int N, int K) {
    __shared__ unsigned short As[2][128 * 32];
    __shared__ unsigned short Bs[2][128 * 32];
    const int tid = threadIdx.x;
    const int wid = tid >> 6, lane = tid & 63;
    const size_t brow = (size_t)blockIdx.x * 128, bcol = (size_t)blockIdx.y * 128;
    const int nkt = K >> 5;

    auto stage = [&](int buf, int kt) {
#pragma unroll
        for (int j = 0; j < 2; ++j) {
            int e = (j * 256 + tid) * 8;
            int r = e >> 5, c = e & 31;
            gll16(A + (brow + r) * K + kt * 32 + c, &As[buf][e]);
        }
#pragma unroll
        for (int j = 0; j < 2; ++j) {
            int e = (j * 256 + tid) * 8;
            int r = e >> 5, c = e & 31;
            gll16(Bt + (bcol + r) * K + kt * 32 + c, &Bs[buf][e]);
        }
    };

    f32x4 acc[4][4] = {};
    const int wm = (wid >> 1) * 64, wn = (wid & 1) * 64;
    const int fr = lane & 15, fk = (lane >> 4) * 8;

    stage(0, 0);
    for (int kt = 0; kt < nkt; ++kt) {
        __syncthreads();
        if (kt + 1 < nkt) stage((kt + 1) & 1, kt + 1);
        const int buf = kt & 1;
        bf16x8 af[4], bfr[4];
#pragma unroll
        for (int i = 0; i < 4; ++i)
            af[i] = *(const bf16x8*)&As[buf][(wm + i * 16 + fr) * 32 + fk];
#pragma unroll
        for (int i = 0; i < 4; ++i)
            bfr[i] = *(const bf16x8*)&Bs[buf][(wn + i * 16 + fr) * 32 + fk];
#pragma unroll
        for (int i = 0; i < 4; ++i)
#pragma unroll
            for (int j = 0; j < 4; ++j)
                acc[i][j] = MFMA16(af[i], bfr[j], acc[i][j]);
    }

    const int orow = (lane >> 4) * 4, ocol = lane & 15;
#pragma unroll
    for (int i = 0; i < 4; ++i)
#pragma unroll
        for (int j = 0; j < 4; ++j)
#pragma unroll
            for (int r = 0; r < 4; ++r)
                C[(brow + wm + i * 16 + orow + r) * N + (bcol + wn + j * 16 + ocol)] =
                    acc[i][j][r];
}

// ---------------- RoPE + QK-RMSNorm + layout split (q pre-scaled by 1/sqrt(D)) ----------------
__global__ __launch_bounds__(256) void rope_norm(const float* __restrict__ qkv,
                                                 const float2* __restrict__ tbl,
                                                 unsigned short* __restrict__ qb,
                                                 unsigned short* __restrict__ kb,
                                                 unsigned short* __restrict__ vb) {
    int unit = blockIdx.x * 4 + (threadIdx.x >> 6);
    int lane = threadIdx.x & 63;
    int row = unit / 24;
    int hh = unit - row * 24;
    int b = row >> 11, t = row & 2047;
    int col = (hh < 16) ? hh * 64 : (hh < 20 ? 1024 + (hh - 16) * 64 : 1280 + (hh - 20) * 64);
    float x = qkv[(size_t)row * 1536 + col + lane];
    float o = x;
    if (hh < 20) {
        float partner = __shfl_xor(x, 1);
        float2 cs = tbl[t * 32 + (lane >> 1)];
        float sgn = (lane & 1) ? cs.y : -cs.y;
        o = x * cs.x + partner * sgn;
        float ss = o * o;
#pragma unroll
        for (int off = 1; off < 64; off <<= 1) ss += __shfl_xor(ss, off);
        o = o * rsqrtf(ss * (1.0f / 64.0f) + 1e-6f);
        if (hh < 16) o *= 0.125f;
    }
    unsigned short ob = f2bf(o);
    if (hh < 16)
        qb[(((size_t)(b * 16 + hh)) * 2048 + t) * 64 + lane] = ob;
    else if (hh < 20)
        kb[(((size_t)(b * 4 + (hh - 16))) * 2048 + t) * 64 + lane] = ob;
    else
        vb[(((size_t)(b * 4 + (hh - 20))) * 2048 + t) * 64 + lane] = ob;
}

// ---------------- V transpose: [B*KVH][T][D] -> [B*KVH][D][T] ----------------
__global__ __launch_bounds__(256) void vtrans(const unsigned short* __restrict__ vb,
                                              unsigned short* __restrict__ vt) {
    __shared__ unsigned short tile[64][72];
    int bk = blockIdx.y, t0 = blockIdx.x * 64;
    int i = threadIdx.x >> 2, c0 = (threadIdx.x & 3) * 16;
    const unsigned short* src = vb + ((size_t)bk * 2048 + t0) * 64;
#pragma unroll
    for (int j = 0; j < 16; ++j) tile[i][c0 + j] = src[i * 64 + c0 + j];
    __syncthreads();
    unsigned short* dst = vt + (size_t)bk * 64 * 2048 + (size_t)i * 2048 + t0 + c0;
#pragma unroll
    for (int j = 0; j < 16; ++j) dst[j] = tile[c0 + j][i];
}

// ---------------- causal flash attention: 32x32 MFMA, in-register softmax (T12) ----------------
// Swapped QK^T; P->A-fragment in registers (cvt_pk + permlane32_swap). Static-max softmax
// (p=exp(s-8)); lrun via v_pk_add_f32 pairs. Wave-uniform diag branch: mask ops only on
// diagonal tiles. K/V LDS swizzle rho(row)=(row&7)^((row>>3)&3) on both staging source and
// read (involution both sides). kv-split chunks + fp32 atomics; XCD-chunked grid.
__global__ __launch_bounds__(256) void attn_fwd(const unsigned short* __restrict__ qb,
                                                const unsigned short* __restrict__ kbuf,
                                                const unsigned short* __restrict__ vt,
                                                float* __restrict__ accOg,
                                                float* __restrict__ accLg) {
    // XCD-chunked bijective swizzle (nwg=2560 = 8*320; 320 = 8 bh per XCD chunk)
    int orig = blockIdx.x;
    int wg = (orig & 7) * 320 + (orig >> 3);
    int bh = wg / 40;
    int u = 39 - (wg - bh * 40);          // heavy-first (large qt first)
    int qt, ci, nc;
    if (u < 4)       { qt = u;               ci = 0;            nc = 1; }
    else if (u < 12) { qt = 4 + ((u - 4) >> 1);  ci = (u - 4) & 1;  nc = 2; }
    else if (u < 24) { qt = 8 + (u - 12) / 3;    ci = (u - 12) % 3; nc = 3; }
    else             { qt = 12 + ((u - 24) >> 2); ci = (u - 24) & 3; nc = 4; }
    const int nkt = 2 * qt + 2;
    const int t0 = ci * nkt / nc, t1 = (ci + 1) * nkt / nc;
    const int qbase = qt * 128;

    int b = bh >> 4, h = bh & 15, kvh = h >> 2;
    int tid = threadIdx.x, wid = tid >> 6, lane = tid & 63;
    int qrow0 = qbase + wid * 32;
    const unsigned short* Q = qb + ((size_t)(b * 16 + h)) * 2048 * 64;
    const unsigned short* Kp = kbuf + ((size_t)(b * 4 + kvh)) * 2048 * 64;
    const unsigned short* Vp = vt + ((size_t)(b * 4 + kvh)) * 64 * 2048;
    const int q32 = lane & 31, hi = lane >> 5;
    const int swz = (q32 & 7) ^ ((q32 >> 3) & 3);   // rho(row), j/nd-independent

    __shared__ unsigned short Klds[2][4096];   // [64 keys][64 d], rho-swizzled chunks
    __shared__ unsigned short Vlds[2][4096];   // [64 d][64 keys], rho-swizzled chunks

    auto stage = [&](int buf, int kt) {
#pragma unroll
        for (int j = 0; j < 2; ++j) {
            int t = j * 256 + tid;
            int k = t >> 3, c = (t & 7) ^ (k & 7) ^ ((k >> 3) & 3);
            gll16(Kp + ((size_t)(kt * 64 + k)) * 64 + c * 8, &Klds[buf][t * 8]);
        }
#pragma unroll
        for (int j = 0; j < 2; ++j) {
            int t = j * 256 + tid;
            int d = t >> 3, c = (t & 7) ^ (d & 7) ^ ((d >> 3) & 3);
            gll16(Vp + (size_t)d * 2048 + kt * 64 + c * 8, &Vlds[buf][t * 8]);
        }
    };

    // Q fragments (B-operand): lane holds Q[qrow0+q32][kd*16 + hi*8 .. +7]
    bf16x8 qf[4];
#pragma unroll
    for (int kd = 0; kd < 4; ++kd)
        qf[kd] = *(const bf16x8*)&Q[(qrow0 + q32) * 64 + kd * 16 + hi * 8];

    f32x16 accO[2] = {};
    f32x2 lr2 = {0.0f, 0.0f};

    stage(0, t0);
    for (int kt = t0; kt < t1; ++kt) {
        __syncthreads();                   // drains stage(kt) vmcnt; guards buf reuse
        if (kt + 1 < t1) stage((kt + 1 - t0) & 1, kt + 1);
        const int cur = (kt - t0) & 1;
        const int kb0 = kt * 64;
        if (kb0 <= qrow0 + 31) {           // wave-uniform causal skip
            // S^T = K @ Q^T: two 32-key tiles, 4 d-slices each
            f32x16 s[2] = {};
#pragma unroll
            for (int j = 0; j < 2; ++j) {
                int row = j * 32 + q32;
#pragma unroll
                for (int kd = 0; kd < 4; ++kd) {
                    bf16x8 kf = *(const bf16x8*)&Klds[cur][row * 64 + ((2 * kd + hi) ^ swz) * 8];
                    s[j] = MFMA32(kf, qf[kd], s[j]);
                }
            }
            const int qg = qrow0 + q32;
            bf16x8 pf[4];                  // P fragment, key-slices of 16
            auto build = [&](auto mc) {
                constexpr bool MASKED = decltype(mc)::value;
#pragma unroll
                for (int j = 0; j < 2; ++j) {
                    float p[16];
#pragma unroll
                    for (int r = 0; r < 16; ++r) {
                        float v = __builtin_exp2f(fmaf(s[j][r], 1.44269504f, -11.54156036f));
                        if (MASKED) {
                            int key = kb0 + j * 32 + (r & 3) + 8 * (r >> 2) + 4 * hi;
                            if (key > qg) v = 0.0f;
                        }
                        p[r] = v;
                    }
#pragma unroll
                    for (int i = 0; i < 8; ++i) {
                        f32x2 pp = {p[2 * i], p[2 * i + 1]};
                        asm("v_pk_add_f32 %0, %0, %1" : "+v"(lr2) : "v"(pp));
                    }
#pragma unroll
                    for (int kl = 0; kl < 2; ++kl) {
                        unsigned c0 = cvt_pk_bf16(p[8 * kl + 0], p[8 * kl + 1]);
                        unsigned c1 = cvt_pk_bf16(p[8 * kl + 4], p[8 * kl + 5]);
                        unsigned c2 = cvt_pk_bf16(p[8 * kl + 2], p[8 * kl + 3]);
                        unsigned c3 = cvt_pk_bf16(p[8 * kl + 6], p[8 * kl + 7]);
                        permswap(c0, c1);  // c0 = word0, c1 = word2
                        permswap(c2, c3);  // c2 = word1, c3 = word3
                        union { bf16x8 v; unsigned u[4]; } pk;
                        pk.u[0] = c0; pk.u[1] = c2; pk.u[2] = c1; pk.u[3] = c3;
                        pf[j * 2 + kl] = pk.v;
                    }
                }
            };
            if (kb0 + 63 > qrow0) build(BoolC<true>{});   // diagonal tile: apply mask
            else                  build(BoolC<false>{});  // interior: no mask ops
            // O += P @ V : V^T rows (d) contiguous over keys in Vlds
#pragma unroll
            for (int nd = 0; nd < 2; ++nd) {
                int row = nd * 32 + q32;
#pragma unroll
                for (int ks = 0; ks < 4; ++ks) {
                    bf16x8 vf = *(const bf16x8*)&Vlds[cur][row * 64 + ((2 * ks + hi) ^ swz) * 8];
                    accO[nd] = MFMA32(pf[ks], vf, accO[nd]);
                }
            }
        }
    }

    // cross-half denominator merge: lane halves hold disjoint key subsets for same q
    float lrun = lr2[0] + lr2[1];
    unsigned lu = __builtin_bit_cast(unsigned, lrun);
    unsigned la = lu, lb = lu;
    permswap(la, lb);
    float L = __builtin_bit_cast(float, la) + __builtin_bit_cast(float, lb);

    // additive combine: fp32 atomics into zeroed partial buffers
    if (t0 * 64 <= qrow0 + 31) {
#pragma unroll
        for (int nd = 0; nd < 2; ++nd)
#pragma unroll
            for (int r = 0; r < 16; ++r) {
                int rowq = qrow0 + (r & 3) + 8 * (r >> 2) + 4 * hi;
                atomicAdd(accOg + ((size_t)bh * 2048 + rowq) * 64 + nd * 32 + q32, accO[nd][r]);
            }
        if (lane < 32) atomicAdd(accLg + (size_t)bh * 2048 + qrow0 + q32, L);
    }
}

// ---------------- finalize: y = accO / accL -> bf16 [b][t][h*64+d] ----------------
__global__ __launch_bounds__(256) void attn_fin(const float* __restrict__ accOg,
                                                const float* __restrict__ accLg,
                                                unsigned short* __restrict__ y) {
    int idx = blockIdx.x * 256 + threadIdx.x;   // 2,097,152 = 64*2048*16
    int dg = idx & 15;
    int row = idx >> 4;
    int bh = row >> 11, t = row & 2047;
    int b = bh >> 4, h = bh & 15;
    f32x4 o = *(const f32x4*)&accOg[(size_t)row * 64 + dg * 4];
    float inv = 1.0f / accLg[row];
    ushort4 w;
    w.x = f2bf(o[0] * inv); w.y = f2bf(o[1] * inv);
    w.z = f2bf(o[2] * inv); w.w = f2bf(o[3] * inv);
    *(ushort4*)&y[((size_t)(b * 2048 + t)) * 1024 + h * 64 + dg * 4] = w;
}

extern "C" void kernel_launch(void* const* d_in, const int* in_sizes, int n_in,
                              void* d_out, int out_size, void* d_ws, size_t ws_size,
                              hipStream_t stream) {
    const float* x = (const float*)d_in[0];
    const float* wq = (const float*)d_in[1];
    const float* wk = (const float*)d_in[2];
    const float* wv = (const float*)d_in[3];
    const float* wo = (const float*)d_in[4];
    float* out = (float*)d_out;

    char* ws = (char*)d_ws;
    size_t off = 0;
    auto alloc = [&](size_t bytes) {
        void* p = ws + off;
        off += (bytes + 255) & ~(size_t)255;
        return p;
    };
    unsigned short* xb    = (unsigned short*)alloc(8192ull * 1024 * 2);   // dead after gemm1; reused as ybf
    unsigned short* wqkvb = (unsigned short*)alloc(1536ull * 1024 * 2);
    unsigned short* wob   = (unsigned short*)alloc(1024ull * 1024 * 2);
    float*          qkv   = (float*)alloc(8192ull * 1536 * 4);            // dead after rope_norm; reused as accO/accL
    float2*         tbl   = (float2*)alloc(2048ull * 32 * 8);
    unsigned short* qb    = (unsigned short*)alloc(8192ull * 1024 * 2);
    unsigned short* kb    = (unsigned short*)alloc(4ull * 4 * 2048 * 64 * 2);
    unsigned short* vb    = (unsigned short*)alloc(4ull * 4 * 2048 * 64 * 2);
    unsigned short* vt    = (unsigned short*)alloc(4ull * 4 * 64 * 2048 * 2);

    float*          accO  = qkv;                                 // 64*2048*64 f32 = 32MB
    float*          accL  = qkv + 64ull * 2048 * 64;             // 64*2048 f32 = 512KB
    unsigned short* ybf   = xb;                                  // 16MB

    cvt_f32_bf16<<<(2097152 + 255) / 256, 256, 0, stream>>>((const float4*)x, (ushort4*)xb, 2097152);
    cvt_f32_bf16<<<(262144 + 255) / 256, 256, 0, stream>>>((const float4*)wq, (ushort4*)wqkvb, 262144);
    cvt_f32_bf16<<<(65536 + 255) / 256, 256, 0, stream>>>((const float4*)wk, (ushort4*)(wqkvb + 1048576), 65536);
    cvt_f32_bf16<<<(65536 + 255) / 256, 256, 0, stream>>>((const float4*)wv, (ushort4*)(wqkvb + 1310720), 65536);
    cvt_f32_bf16<<<(262144 + 255) / 256, 256, 0, stream>>>((const float4*)wo, (ushort4*)wob, 262144);

    trig_table<<<256, 256, 0, stream>>>(tbl);

    gemm_bt<<<dim3(64, 12), 256, 0, stream>>>(xb, wqkvb, qkv, 8192, 1536, 1024);

    rope_norm<<<(8192 * 24) / 4, 256, 0, stream>>>(qkv, tbl, qb, kb, vb);

    vtrans<<<dim3(32, 16), 256, 0, stream>>>(vb, vt);

    // zero partial buffers (qkv is dead now); stream-ordered after rope_norm
    hipMemsetAsync(accO, 0, (64ull * 2048 * 64 + 64ull * 2048) * 4, stream);

    attn_fwd<<<2560, 256, 0, stream>>>(qb, kb, vt, accO, accL);

    attn_fin<<<8192, 256, 0, stream>>>(accO, accL, ybf);

    gemm_bt<<<dim3(64, 8), 256, 0, stream>>>(ybf, wob, out, 8192, 1024, 1024);
}

// Round 8
// 203.737 us; speedup vs baseline: 1.1887x; 1.0532x over previous
//
#include <hip/hip_runtime.h>
#include <hip/hip_bf16.h>
#include <type_traits>

typedef __attribute__((ext_vector_type(8))) __bf16 bf16x8;
typedef __attribute__((ext_vector_type(2))) float f32x2;
typedef __attribute__((ext_vector_type(4))) float f32x4;
typedef __attribute__((ext_vector_type(16))) float f32x16;

#define MFMA16(a, b, c) __builtin_amdgcn_mfma_f32_16x16x32_bf16((a), (b), (c), 0, 0, 0)
#define MFMA32(a, b, c) __builtin_amdgcn_mfma_f32_32x32x16_bf16((a), (b), (c), 0, 0, 0)

template <bool B> struct BoolC { static constexpr bool value = B; };

__device__ __forceinline__ unsigned short f2bf(float f) {
    unsigned u = __builtin_bit_cast(unsigned, f);
    u = (u + 0x7fffu + ((u >> 16) & 1u)) >> 16;
    return (unsigned short)u;
}

__device__ __forceinline__ float bf2f(unsigned short u) {
    return __builtin_bit_cast(float, (unsigned)u << 16);
}

__device__ __forceinline__ unsigned cvt_pk_bf16(float lo, float hi) {
    unsigned r;
    asm("v_cvt_pk_bf16_f32 %0, %1, %2" : "=v"(r) : "v"(lo), "v"(hi));
    return r;
}

// swaps a.hi32lanes <-> b.lo32lanes
__device__ __forceinline__ void permswap(unsigned& a, unsigned& b) {
    asm("v_permlane32_swap_b32 %0, %1" : "+v"(a), "+v"(b));
}

__device__ __forceinline__ void gll16(const void* g, void* l) {
    __builtin_amdgcn_global_load_lds((const __attribute__((address_space(1))) void*)g,
                                     (__attribute__((address_space(3))) void*)l, 16, 0, 0);
}

// ---------------- fused fp32->bf16 converts + trig table (one launch) ----------------
// units: [0,2752512) = float4 converts over 5 regions; [2752512, 2818048) = trig entries.
__global__ __launch_bounds__(256) void cvt_fused(const float4* __restrict__ x,
                                                 const float4* __restrict__ wq,
                                                 const float4* __restrict__ wk,
                                                 const float4* __restrict__ wv,
                                                 const float4* __restrict__ wo,
                                                 ushort4* __restrict__ xb,
                                                 ushort4* __restrict__ wqkvb,
                                                 ushort4* __restrict__ wob,
                                                 float2* __restrict__ tbl) {
    int i = blockIdx.x * 256 + threadIdx.x;
    if (i < 2752512) {
        const float4* src; ushort4* dst; int j;
        if (i < 2097152)      { src = x;  dst = xb;             j = i; }
        else if (i < 2359296) { src = wq; dst = wqkvb;          j = i - 2097152; }
        else if (i < 2424832) { src = wk; dst = wqkvb + 262144; j = i - 2359296; }
        else if (i < 2490368) { src = wv; dst = wqkvb + 327680; j = i - 2424832; }
        else                  { src = wo; dst = wob;            j = i - 2490368; }
        float4 v = src[j];
        ushort4 o;
        o.x = f2bf(v.x); o.y = f2bf(v.y); o.z = f2bf(v.z); o.w = f2bf(v.w);
        dst[j] = o;
    } else {
        int j = i - 2752512;              // 65536 = 2048*32
        int t = j >> 5, k = j & 31;
        float inv = powf(10000.0f, -(float)(2 * k) * (1.0f / 64.0f));
        float a = (float)t * inv;
        tbl[j] = make_float2(cosf(a), sinf(a));
    }
}

// ---------------- GEMM: C(MxN) = A(MxK) @ Bt(NxK)^T, bf16 in, fp32/bf16 out ----------------
template <typename OT>
__global__ __launch_bounds__(256) void gemm_bt_t(const unsigned short* __restrict__ A,
                                                 const unsigned short* __restrict__ Bt,
                                                 OT* __restrict__ C, int M, int N, int K) {
    __shared__ unsigned short As[2][128 * 32];
    __shared__ unsigned short Bs[2][128 * 32];
    const int tid = threadIdx.x;
    const int wid = tid >> 6, lane = tid & 63;
    const size_t brow = (size_t)blockIdx.x * 128, bcol = (size_t)blockIdx.y * 128;
    const int nkt = K >> 5;

    auto stage = [&](int buf, int kt) {
#pragma unroll
        for (int j = 0; j < 2; ++j) {
            int e = (j * 256 + tid) * 8;
            int r = e >> 5, c = e & 31;
            gll16(A + (brow + r) * K + kt * 32 + c, &As[buf][e]);
        }
#pragma unroll
        for (int j = 0; j < 2; ++j) {
            int e = (j * 256 + tid) * 8;
            int r = e >> 5, c = e & 31;
            gll16(Bt + (bcol + r) * K + kt * 32 + c, &Bs[buf][e]);
        }
    };

    f32x4 acc[4][4] = {};
    const int wm = (wid >> 1) * 64, wn = (wid & 1) * 64;
    const int fr = lane & 15, fk = (lane >> 4) * 8;

    stage(0, 0);
    for (int kt = 0; kt < nkt; ++kt) {
        __syncthreads();
        if (kt + 1 < nkt) stage((kt + 1) & 1, kt + 1);
        const int buf = kt & 1;
        bf16x8 af[4], bfr[4];
#pragma unroll
        for (int i = 0; i < 4; ++i)
            af[i] = *(const bf16x8*)&As[buf][(wm + i * 16 + fr) * 32 + fk];
#pragma unroll
        for (int i = 0; i < 4; ++i)
            bfr[i] = *(const bf16x8*)&Bs[buf][(wn + i * 16 + fr) * 32 + fk];
#pragma unroll
        for (int i = 0; i < 4; ++i)
#pragma unroll
            for (int j = 0; j < 4; ++j)
                acc[i][j] = MFMA16(af[i], bfr[j], acc[i][j]);
    }

    const int orow = (lane >> 4) * 4, ocol = lane & 15;
#pragma unroll
    for (int i = 0; i < 4; ++i)
#pragma unroll
        for (int j = 0; j < 4; ++j)
#pragma unroll
            for (int r = 0; r < 4; ++r) {
                size_t idx = (brow + wm + i * 16 + orow + r) * N + (bcol + wn + j * 16 + ocol);
                if constexpr (std::is_same_v<OT, unsigned short>)
                    C[idx] = f2bf(acc[i][j][r]);
                else
                    C[idx] = acc[i][j][r];
            }
}

// ---------------- RoPE + QK-RMSNorm (bf16 qkv in); q pre-scaled by 0.125*log2e ----------------
__global__ __launch_bounds__(256) void rope_norm(const unsigned short* __restrict__ qkvb,
                                                 const float2* __restrict__ tbl,
                                                 unsigned short* __restrict__ qb,
                                                 unsigned short* __restrict__ kb) {
    int unit = blockIdx.x * 4 + (threadIdx.x >> 6);  // 8192*20 units (16 q + 4 k heads)
    int lane = threadIdx.x & 63;
    int row = unit / 20;
    int hh = unit - row * 20;
    int b = row >> 11, t = row & 2047;
    int col = (hh < 16) ? hh * 64 : 1024 + (hh - 16) * 64;
    float x = bf2f(qkvb[(size_t)row * 1536 + col + lane]);
    float partner = __shfl_xor(x, 1);
    float2 cs = tbl[t * 32 + (lane >> 1)];
    float sgn = (lane & 1) ? cs.y : -cs.y;
    float o = x * cs.x + partner * sgn;
    float ss = o * o;
#pragma unroll
    for (int off = 1; off < 64; off <<= 1) ss += __shfl_xor(ss, off);
    o = o * rsqrtf(ss * (1.0f / 64.0f) + 1e-6f);
    if (hh < 16) o *= 0.18033688f;   // 1/sqrt(64) * log2(e), folded into q
    unsigned short ob = f2bf(o);
    if (hh < 16)
        qb[(((size_t)(b * 16 + hh)) * 2048 + t) * 64 + lane] = ob;
    else
        kb[(((size_t)(b * 4 + (hh - 16))) * 2048 + t) * 64 + lane] = ob;
}

// ---------------- V transpose from qkv v-region: -> [B*KVH][D][T] ----------------
__global__ __launch_bounds__(256) void vtrans(const unsigned short* __restrict__ qkvb,
                                              unsigned short* __restrict__ vt) {
    __shared__ unsigned short tile[64][72];
    int bk = blockIdx.y, t0 = blockIdx.x * 64;
    int b = bk >> 2, kvh = bk & 3;
    int i = threadIdx.x >> 2, c0 = (threadIdx.x & 3) * 16;
    const unsigned short* src = qkvb + ((size_t)(b * 2048 + t0)) * 1536 + 1280 + kvh * 64;
#pragma unroll
    for (int j = 0; j < 16; ++j) tile[i][c0 + j] = src[(size_t)i * 1536 + c0 + j];
    __syncthreads();
    unsigned short* dst = vt + (size_t)bk * 64 * 2048 + (size_t)i * 2048 + t0 + c0;
#pragma unroll
    for (int j = 0; j < 16; ++j) dst[j] = tile[c0 + j][i];
}

// ---------------- causal flash attention ----------------
// 32x32 MFMA, in-register softmax (T12), static-max p=exp2(s + S0) with log2e folded into q
// and S0 into the accumulator init (no per-element fma). Counted-vmcnt 3-buffer staging
// (T3/T4): raw s_barrier + s_waitcnt vmcnt(4), one stage (4 gll16) always in flight.
// setprio around MFMA clusters (T5). kv-split chunks + fp32 atomics; XCD-chunked grid.
__global__ __launch_bounds__(256) void attn_fwd(const unsigned short* __restrict__ qb,
                                                const unsigned short* __restrict__ kbuf,
                                                const unsigned short* __restrict__ vt,
                                                float* __restrict__ accOg,
                                                float* __restrict__ accLg) {
    // XCD-chunked bijective swizzle (nwg=2560 = 8*320; 320 = 8 bh per XCD chunk)
    int orig = blockIdx.x;
    int wg = (orig & 7) * 320 + (orig >> 3);
    int bh = wg / 40;
    int u = 39 - (wg - bh * 40);          // heavy-first (large qt first)
    int qt, ci, nc;
    if (u < 4)       { qt = u;               ci = 0;            nc = 1; }
    else if (u < 12) { qt = 4 + ((u - 4) >> 1);  ci = (u - 4) & 1;  nc = 2; }
    else if (u < 24) { qt = 8 + (u - 12) / 3;    ci = (u - 12) % 3; nc = 3; }
    else             { qt = 12 + ((u - 24) >> 2); ci = (u - 24) & 3; nc = 4; }
    const int nkt = 2 * qt + 2;
    const int t0 = ci * nkt / nc, t1 = (ci + 1) * nkt / nc;
    const int qbase = qt * 128;

    int b = bh >> 4, h = bh & 15, kvh = h >> 2;
    int tid = threadIdx.x, wid = tid >> 6, lane = tid & 63;
    int qrow0 = qbase + wid * 32;
    const unsigned short* Q = qb + ((size_t)(b * 16 + h)) * 2048 * 64;
    const unsigned short* Kp = kbuf + ((size_t)(b * 4 + kvh)) * 2048 * 64;
    const unsigned short* Vp = vt + ((size_t)(b * 4 + kvh)) * 64 * 2048;
    const int q32 = lane & 31, hi = lane >> 5;
    const int swz = (q32 & 7) ^ ((q32 >> 3) & 3);   // rho(row), j/nd-independent

    __shared__ unsigned short Klds[3][4096];   // [64 keys][64 d], rho-swizzled chunks
    __shared__ unsigned short Vlds[3][4096];   // [64 d][64 keys], rho-swizzled chunks

    auto stage = [&](int buf, int kt) {        // 4 gll16 per thread
#pragma unroll
        for (int j = 0; j < 2; ++j) {
            int t = j * 256 + tid;
            int k = t >> 3, c = (t & 7) ^ (k & 7) ^ ((k >> 3) & 3);
            gll16(Kp + ((size_t)(kt * 64 + k)) * 64 + c * 8, &Klds[buf][t * 8]);
        }
#pragma unroll
        for (int j = 0; j < 2; ++j) {
            int t = j * 256 + tid;
            int d = t >> 3, c = (t & 7) ^ (d & 7) ^ ((d >> 3) & 3);
            gll16(Vp + (size_t)d * 2048 + kt * 64 + c * 8, &Vlds[buf][t * 8]);
        }
    };

    // Q fragments (B-operand): lane holds Q[qrow0+q32][kd*16 + hi*8 .. +7]
    bf16x8 qf[4];
#pragma unroll
    for (int kd = 0; kd < 4; ++kd)
        qf[kd] = *(const bf16x8*)&Q[(qrow0 + q32) * 64 + kd * 16 + hi * 8];

    f32x16 accO[2] = {};
    f32x2 lr2 = {0.0f, 0.0f};
    f32x16 s0v;                            // accumulator init = -8*log2(e)
#pragma unroll
    for (int i = 0; i < 16; ++i) s0v[i] = -11.54156036f;

    const int nt = t1 - t0;
    stage(0, t0);
    if (nt > 1) stage(1, t0 + 1);
    int cur = 0;
    for (int kt = t0; kt < t1; ++kt) {
        if (kt + 1 < t1) { asm volatile("s_waitcnt vmcnt(4)" ::: "memory"); }
        else             { asm volatile("s_waitcnt vmcnt(0)" ::: "memory"); }
        __builtin_amdgcn_sched_barrier(0);
        __builtin_amdgcn_s_barrier();      // raw barrier: no implicit vmcnt(0) drain
        if (kt + 2 < t1) stage(cur == 0 ? 2 : cur - 1, kt + 2);   // (cur+2)%3
        const int kb0 = kt * 64;
        if (kb0 <= qrow0 + 31) {           // wave-uniform causal skip
            // S^T = K @ Q^T: two 32-key tiles, 4 d-slices each; acc starts at S0
            f32x16 s[2] = {s0v, s0v};
            __builtin_amdgcn_s_setprio(1);
#pragma unroll
            for (int j = 0; j < 2; ++j) {
                int row = j * 32 + q32;
#pragma unroll
                for (int kd = 0; kd < 4; ++kd) {
                    bf16x8 kf = *(const bf16x8*)&Klds[cur][row * 64 + ((2 * kd + hi) ^ swz) * 8];
                    s[j] = MFMA32(kf, qf[kd], s[j]);
                }
            }
            __builtin_amdgcn_s_setprio(0);
            const int qg = qrow0 + q32;
            bf16x8 pf[4];                  // P fragment, key-slices of 16
            auto build = [&](auto mc) {
                constexpr bool MASKED = decltype(mc)::value;
#pragma unroll
                for (int j = 0; j < 2; ++j) {
                    float p[16];
#pragma unroll
                    for (int r = 0; r < 16; ++r) {
                        float v = __builtin_exp2f(s[j][r]);
                        if (MASKED) {
                            int key = kb0 + j * 32 + (r & 3) + 8 * (r >> 2) + 4 * hi;
                            if (key > qg) v = 0.0f;
                        }
                        p[r] = v;
                    }
#pragma unroll
                    for (int i = 0; i < 8; ++i) {
                        f32x2 pp = {p[2 * i], p[2 * i + 1]};
                        asm("v_pk_add_f32 %0, %0, %1" : "+v"(lr2) : "v"(pp));
                    }
#pragma unroll
                    for (int kl = 0; kl < 2; ++kl) {
                        unsigned c0 = cvt_pk_bf16(p[8 * kl + 0], p[8 * kl + 1]);
                        unsigned c1 = cvt_pk_bf16(p[8 * kl + 4], p[8 * kl + 5]);
                        unsigned c2 = cvt_pk_bf16(p[8 * kl + 2], p[8 * kl + 3]);
                        unsigned c3 = cvt_pk_bf16(p[8 * kl + 6], p[8 * kl + 7]);
                        permswap(c0, c1);  // c0 = word0, c1 = word2
                        permswap(c2, c3);  // c2 = word1, c3 = word3
                        union { bf16x8 v; unsigned u[4]; } pk;
                        pk.u[0] = c0; pk.u[1] = c2; pk.u[2] = c1; pk.u[3] = c3;
                        pf[j * 2 + kl] = pk.v;
                    }
                }
            };
            if (kb0 + 63 > qrow0) build(BoolC<true>{});   // diagonal tile: apply mask
            else                  build(BoolC<false>{});  // interior: no mask ops
            // O += P @ V : V^T rows (d) contiguous over keys in Vlds
            __builtin_amdgcn_s_setprio(1);
#pragma unroll
            for (int nd = 0; nd < 2; ++nd) {
                int row = nd * 32 + q32;
#pragma unroll
                for (int ks = 0; ks < 4; ++ks) {
                    bf16x8 vf = *(const bf16x8*)&Vlds[cur][row * 64 + ((2 * ks + hi) ^ swz) * 8];
                    accO[nd] = MFMA32(pf[ks], vf, accO[nd]);
                }
            }
            __builtin_amdgcn_s_setprio(0);
        }
        cur = (cur == 2) ? 0 : cur + 1;
    }

    // cross-half denominator merge: lane halves hold disjoint key subsets for same q
    float lrun = lr2[0] + lr2[1];
    unsigned lu = __builtin_bit_cast(unsigned, lrun);
    unsigned la = lu, lb = lu;
    permswap(la, lb);
    float L = __builtin_bit_cast(float, la) + __builtin_bit_cast(float, lb);

    // additive combine: fp32 atomics into zeroed partial buffers
    if (t0 * 64 <= qrow0 + 31) {
#pragma unroll
        for (int nd = 0; nd < 2; ++nd)
#pragma unroll
            for (int r = 0; r < 16; ++r) {
                int rowq = qrow0 + (r & 3) + 8 * (r >> 2) + 4 * hi;
                atomicAdd(accOg + ((size_t)bh * 2048 + rowq) * 64 + nd * 32 + q32, accO[nd][r]);
            }
        if (lane < 32) atomicAdd(accLg + (size_t)bh * 2048 + qrow0 + q32, L);
    }
}

// ---------------- finalize: y = accO / accL -> bf16 [b][t][h*64+d] ----------------
__global__ __launch_bounds__(256) void attn_fin(const float* __restrict__ accOg,
                                                const float* __restrict__ accLg,
                                                unsigned short* __restrict__ y) {
    int idx = blockIdx.x * 256 + threadIdx.x;   // 2,097,152 = 64*2048*16
    int dg = idx & 15;
    int row = idx >> 4;
    int bh = row >> 11, t = row & 2047;
    int b = bh >> 4, h = bh & 15;
    f32x4 o = *(const f32x4*)&accOg[(size_t)row * 64 + dg * 4];
    float inv = 1.0f / accLg[row];
    ushort4 w;
    w.x = f2bf(o[0] * inv); w.y = f2bf(o[1] * inv);
    w.z = f2bf(o[2] * inv); w.w = f2bf(o[3] * inv);
    *(ushort4*)&y[((size_t)(b * 2048 + t)) * 1024 + h * 64 + dg * 4] = w;
}

extern "C" void kernel_launch(void* const* d_in, const int* in_sizes, int n_in,
                              void* d_out, int out_size, void* d_ws, size_t ws_size,
                              hipStream_t stream) {
    const float* x = (const float*)d_in[0];
    const float* wq = (const float*)d_in[1];
    const float* wk = (const float*)d_in[2];
    const float* wv = (const float*)d_in[3];
    const float* wo = (const float*)d_in[4];
    float* out = (float*)d_out;

    char* ws = (char*)d_ws;
    size_t off = 0;
    auto alloc = [&](size_t bytes) {
        void* p = ws + off;
        off += (bytes + 255) & ~(size_t)255;
        return p;
    };
    unsigned short* xb    = (unsigned short*)alloc(8192ull * 1024 * 2);   // dead after gemm1; reused as ybf
    unsigned short* wqkvb = (unsigned short*)alloc(1536ull * 1024 * 2);
    unsigned short* wob   = (unsigned short*)alloc(1024ull * 1024 * 2);
    char*           big   = (char*)alloc((64ull * 2048 * 64 + 64ull * 2048) * 4); // qkvb (24MB) then accO/accL (32.5MB)
    float2*         tbl   = (float2*)alloc(2048ull * 32 * 8);
    unsigned short* qb    = (unsigned short*)alloc(8192ull * 1024 * 2);
    unsigned short* kb    = (unsigned short*)alloc(4ull * 4 * 2048 * 64 * 2);
    unsigned short* vt    = (unsigned short*)alloc(4ull * 4 * 64 * 2048 * 2);

    unsigned short* qkvb  = (unsigned short*)big;                // bf16 [8192][1536], dead after vtrans
    float*          accO  = (float*)big;                         // aliases qkvb (memset after vtrans)
    float*          accL  = accO + 64ull * 2048 * 64;
    unsigned short* ybf   = xb;

    // 1) fused converts + trig (one launch)
    cvt_fused<<<11008, 256, 0, stream>>>((const float4*)x, (const float4*)wq, (const float4*)wk,
                                         (const float4*)wv, (const float4*)wo,
                                         (ushort4*)xb, (ushort4*)wqkvb, (ushort4*)wob, tbl);

    // 2) QKV GEMM -> bf16 [8192x1536]
    gemm_bt_t<unsigned short><<<dim3(64, 12), 256, 0, stream>>>(xb, wqkvb, qkvb, 8192, 1536, 1024);

    // 3) RoPE + QK-norm (q,k only; q pre-scaled by 0.125*log2e)
    rope_norm<<<(8192 * 20) / 4, 256, 0, stream>>>(qkvb, tbl, qb, kb);

    // 4) V transpose straight from qkv v-region
    vtrans<<<dim3(32, 16), 256, 0, stream>>>(qkvb, vt);

    // 5) zero partial buffers (qkvb dead now; accO aliases it)
    hipMemsetAsync(accO, 0, (64ull * 2048 * 64 + 64ull * 2048) * 4, stream);

    // 6) attention partials
    attn_fwd<<<2560, 256, 0, stream>>>(qb, kb, vt, accO, accL);

    // 7) finalize
    attn_fin<<<8192, 256, 0, stream>>>(accO, accL, ybf);

    // 8) output GEMM -> fp32 d_out
    gemm_bt_t<float><<<dim3(64, 8), 256, 0, stream>>>(ybf, wob, out, 8192, 1024, 1024);
}